// Round 3
// baseline (401.889 us; speedup 1.0000x reference)
//
#include <hip/hip_runtime.h>
#include <hip/hip_bf16.h>
#include <cstdint>
#include <cstddef>

namespace {

constexpr int BB  = 4;      // batch
constexpr int LL  = 2048;   // seq
constexpr int DM  = 256;    // d_model
constexpr int DI  = 512;    // d_inner
constexpr int DFF = 1024;
constexpr float EPSV = 1e-5f;
constexpr int BL  = BB * LL;     // 8192 rows per direction
constexpr int M2  = 2 * BL;      // 16384 rows (both dirs)
constexpr int NCH = 8;           // scan chunks
constexpr int CHL = LL / NCH;    // 256 timesteps per chunk
constexpr int NCHAIN = 2 * BB * DI;   // 4096 scan chains

typedef __attribute__((ext_vector_type(8))) short bf16x8;
typedef __attribute__((ext_vector_type(4))) float f32x4;

__device__ __forceinline__ float fsilu(float v) { return v / (1.f + __expf(-v)); }

__device__ __forceinline__ short f2bf(float f) {
  union { float f; uint32_t u; } v; v.f = f;
  uint32_t r = (v.u + 0x7fffu + ((v.u >> 16) & 1u)) >> 16;
  return (short)r;
}

__device__ __forceinline__ void gld16(const short* g, short* l) {
  __builtin_amdgcn_global_load_lds(
      (const __attribute__((address_space(1))) void*)g,
      (__attribute__((address_space(3))) void*)l, 16, 0, 0);
}

// ---------------------------------------------------------------------------
// f32 -> bf16 convert, 4 elems/thread, n % 1024 == 0
// ---------------------------------------------------------------------------
__global__ __launch_bounds__(256) void cvt_kernel(
    const float* __restrict__ in, short* __restrict__ out, int n)
{
  int i = (blockIdx.x * 256 + threadIdx.x) * 4;
  if (i >= n) return;
  float4 v = *reinterpret_cast<const float4*>(in + i);
  ushort4 o;
  o.x = (unsigned short)f2bf(v.x); o.y = (unsigned short)f2bf(v.y);
  o.z = (unsigned short)f2bf(v.z); o.w = (unsigned short)f2bf(v.w);
  *reinterpret_cast<ushort4*>(out + i) = o;
}

// ---------------------------------------------------------------------------
// bf16 MFMA GEMM, 128x128 tile, BK=32, 4 waves of 64x64, fp32 accum.
// ---------------------------------------------------------------------------
template <int EP>
__global__ __launch_bounds__(256) void mgemm(
    const short* __restrict__ A, const short* __restrict__ W,
    float* __restrict__ Cf, short* __restrict__ Ch, int N, int K,
    const float* __restrict__ P0, const float* __restrict__ P1,
    const float* __restrict__ P2, const float* __restrict__ P3,
    const float* __restrict__ P4, const float* __restrict__ P5)
{
  __shared__ short As[128 * 32];
  __shared__ short Bs[128 * 32];
  const int tid  = threadIdx.x;
  const int lane = tid & 63, wv = tid >> 6;
  const int wrow = (wv >> 1) * 64, wcol = (wv & 1) * 64;
  const int row0 = blockIdx.y * 128, col0 = blockIdx.x * 128;
  const int dir  = (EP == 0 || EP == 1) ? (row0 >= BL ? 1 : 0) : 0;
  const short* Wp = W + (size_t)dir * (size_t)N * (size_t)K;

  f32x4 acc[4][4];
#pragma unroll
  for (int m = 0; m < 4; ++m)
#pragma unroll
    for (int n = 0; n < 4; ++n) acc[m][n] = (f32x4){0.f, 0.f, 0.f, 0.f};

  for (int k0 = 0; k0 < K; k0 += 32) {
#pragma unroll
    for (int s = 0; s < 2; ++s) {
      int f = s * 256 + wv * 64 + lane;      // [0,512)
      int rr = f >> 2, kc = f & 3;           // tile row, 16B chunk along k
      const short* asrc;
      if (EP == 0) {
        int r  = row0 + rr;
        int rb = r & (BL - 1);
        int b = rb >> 11, t = rb & (LL - 1);
        int torig = dir ? (LL - 1 - t) : t;
        asrc = A + ((size_t)(b * LL + torig)) * K + k0 + kc * 8;
      } else {
        asrc = A + (size_t)(row0 + rr) * K + k0 + kc * 8;
      }
      const short* bsrc = Wp + (size_t)(col0 + rr) * K + k0 + kc * 8;
      gld16(asrc, &As[(s * 256 + wv * 64) * 8]);   // wave-uniform LDS base
      gld16(bsrc, &Bs[(s * 256 + wv * 64) * 8]);
    }
    __syncthreads();
    bf16x8 af[4], bfr[4];
    const int krow = (lane >> 4) * 8;
#pragma unroll
    for (int m = 0; m < 4; ++m)
      af[m] = *reinterpret_cast<const bf16x8*>(&As[(wrow + m * 16 + (lane & 15)) * 32 + krow]);
#pragma unroll
    for (int n = 0; n < 4; ++n)
      bfr[n] = *reinterpret_cast<const bf16x8*>(&Bs[(wcol + n * 16 + (lane & 15)) * 32 + krow]);
#pragma unroll
    for (int m = 0; m < 4; ++m)
#pragma unroll
      for (int n = 0; n < 4; ++n)
        acc[m][n] = __builtin_amdgcn_mfma_f32_16x16x32_bf16(af[m], bfr[n], acc[m][n], 0, 0, 0);
    __syncthreads();
  }

  // epilogue: C/D layout col=lane&15, row=(lane>>4)*4+reg
#pragma unroll
  for (int m = 0; m < 4; ++m) {
#pragma unroll
    for (int i = 0; i < 4; ++i) {
      int r = row0 + wrow + m * 16 + (lane >> 4) * 4 + i;
      size_t obase;
      if (EP == 1) {
        int rb = r & (BL - 1);
        int b = rb >> 11, t = rb & (LL - 1);
        int torig = dir ? (LL - 1 - t) : t;
        obase = ((size_t)(dir * BB + b) * LL + torig) * DM;
      } else {
        obase = (size_t)r * N;
      }
#pragma unroll
      for (int n = 0; n < 4; ++n) {
        int c = col0 + wcol + n * 16 + (lane & 15);
        float val = acc[m][n][i];
        if (EP == 1) {
          int o = dir * DM + c;
          val = (val - P2[o]) * rsqrtf(P3[o] + EPSV) * P0[o] + P1[o];
          Cf[obase + c] = val;
        } else if (EP == 2) {
          val = fmaxf(val + P0[c], 0.f);
          Ch[obase + c] = f2bf(val);
        } else if (EP == 3) {
          val = val + P0[c];
          int o = 2 * DM + c;
          val = (val - P3[o]) * rsqrtf(P4[o] + EPSV) * P1[o] + P2[o];
          val += P5[obase + c];
          Cf[obase + c] = val;
        } else {
          Cf[obase + c] = val;
        }
      }
    }
  }
}

// ---------------------------------------------------------------------------
// causal depthwise conv (taps=4) + bias + SiLU.
// ---------------------------------------------------------------------------
__global__ __launch_bounds__(256) void conv_silu_kernel(
    const float* __restrict__ XZ, const float* __restrict__ cw,
    const float* __restrict__ cb, float* __restrict__ XI)
{
  int idx = blockIdx.x * 256 + threadIdx.x;
  int d = idx & 511;
  int r = idx >> 9;
  int t = r & (LL - 1);
  int db = r >> 11;
  int dir = db >> 2;
  size_t base = (size_t)db * LL * 1024 + d;
  const float* w = cw + (size_t)(dir * DI + d) * 4;
  float acc = cb[dir * DI + d];
#pragma unroll
  for (int j = 0; j < 4; ++j) {
    int tp = t - 3 + j;
    if (tp >= 0) acc = fmaf(w[j], XZ[base + (size_t)tp * 1024], acc);
  }
  XI[idx] = fsilu(acc);
}

// ---------------------------------------------------------------------------
// xproj: DBC(M2 x 48) = XI(M2 x 512) @ xproj_w(dir)^T.  64-row tiles, fp32.
// ---------------------------------------------------------------------------
__global__ __launch_bounds__(256) void xproj_kernel(
    const float* __restrict__ XI, const float* __restrict__ W, float* __restrict__ DBC)
{
  __shared__ __align__(16) float As[64 * 68];   // [k][row]
  __shared__ __align__(16) float Ws[64 * 52];   // [k][col]
  const int tid = threadIdx.x;
  const int row0 = blockIdx.x * 64;
  const int dir = row0 >= BL ? 1 : 0;
  const float* Wp = W + (size_t)dir * 48 * DI;
  const int TX = tid & 15, TY = tid >> 4;
  float acc[4][3];
#pragma unroll
  for (int i = 0; i < 4; ++i)
#pragma unroll
    for (int j = 0; j < 3; ++j) acc[i][j] = 0.f;

  for (int k0 = 0; k0 < DI; k0 += 64) {
#pragma unroll
    for (int s = 0; s < 4; ++s) {
      int f = tid + s * 256;
      int kq = f & 15, m = f >> 4;
      float4 v = *reinterpret_cast<const float4*>(XI + (size_t)(row0 + m) * DI + k0 + kq * 4);
      int kk = kq * 4;
      As[(kk + 0) * 68 + m] = v.x; As[(kk + 1) * 68 + m] = v.y;
      As[(kk + 2) * 68 + m] = v.z; As[(kk + 3) * 68 + m] = v.w;
    }
#pragma unroll
    for (int s = 0; s < 3; ++s) {
      int f = tid + s * 256;
      int kq = f & 15, n = f >> 4;
      float4 v = *reinterpret_cast<const float4*>(Wp + (size_t)n * DI + k0 + kq * 4);
      int kk = kq * 4;
      Ws[(kk + 0) * 52 + n] = v.x; Ws[(kk + 1) * 52 + n] = v.y;
      Ws[(kk + 2) * 52 + n] = v.z; Ws[(kk + 3) * 52 + n] = v.w;
    }
    __syncthreads();
    for (int k = 0; k < 64; ++k) {
      float a[4], b[3];
#pragma unroll
      for (int i = 0; i < 4; ++i) a[i] = As[k * 68 + TY * 4 + i];
#pragma unroll
      for (int j = 0; j < 3; ++j) b[j] = Ws[k * 52 + TX * 3 + j];
#pragma unroll
      for (int i = 0; i < 4; ++i)
#pragma unroll
        for (int j = 0; j < 3; ++j) acc[i][j] = fmaf(a[i], b[j], acc[i][j]);
    }
    __syncthreads();
  }
#pragma unroll
  for (int i = 0; i < 4; ++i)
#pragma unroll
    for (int j = 0; j < 3; ++j)
      DBC[(size_t)(row0 + TY * 4 + i) * 48 + TX * 3 + j] = acc[i][j];
}

// ---------------------------------------------------------------------------
// delta = softplus(dt @ dt_w^T + dt_b); one block per (dir,b,t) row
// ---------------------------------------------------------------------------
__global__ __launch_bounds__(256) void dtproj_kernel(
    const float* __restrict__ DBC, const float* __restrict__ dt_w,
    const float* __restrict__ dt_b, float* __restrict__ DELTA)
{
  int row = blockIdx.x;            // [0, 16384)
  int dir = row >> 13;
  __shared__ float dtv[16];
  if (threadIdx.x < 16) dtv[threadIdx.x] = DBC[(size_t)row * 48 + threadIdx.x];
  __syncthreads();
  for (int dd = threadIdx.x; dd < DI; dd += 256) {
    const float* wrow = dt_w + (size_t)(dir * DI + dd) * 16;
    float a = dt_b[dir * DI + dd];
#pragma unroll
    for (int r = 0; r < 16; ++r) a = fmaf(dtv[r], wrow[r], a);
    float sp = (a > 20.f) ? a : log1pf(__expf(a));
    DELTA[(size_t)row * DI + dd] = sp;
  }
}

// ---------------------------------------------------------------------------
// Chunked SSM scan, pass 1: per (chain, chunk), run recurrence from h0=0.
// Outputs h_end[chunk][chain][16] and sum_dt[chunk][chain].
// grid: 2048 blocks (chunk = bid>>8, 16 chains per block). 32 waves/CU.
// ---------------------------------------------------------------------------
__global__ __launch_bounds__(256) void scan1_kernel(
    const float* __restrict__ DELTA, const float* __restrict__ XI,
    const float* __restrict__ DBC, const float* __restrict__ Alog,
    float* __restrict__ HEND, float* __restrict__ SDT)
{
  const int tid = threadIdx.x;
  const int cl = tid >> 4, n = tid & 15;
  const int chain = (blockIdx.x & 255) * 16 + cl;
  const int chunk = blockIdx.x >> 8;
  const int dir = chain >> 11;
  const int b   = (chain >> 9) & 3;
  const int d   = chain & 511;

  const float An = -__expf(Alog[((size_t)(dir * DI + d)) * 16 + n]);
  const int t0g = chunk * CHL;
  const size_t rowDU = ((size_t)(dir * BB + b) * LL + t0g) * DI + d;
  const size_t rowBC = ((size_t)(dir * BB + b) * LL + t0g) * 48 + 16 + n;

  float h = 0.f, sdt = 0.f;
  float dt_ = DELTA[rowDU], u_ = XI[rowDU], bt_ = DBC[rowBC];
  for (int t = 0; t < CHL; ++t) {
    float dt_c = dt_, u_c = u_, bt_c = bt_;
    if (t + 1 < CHL) {
      size_t r2 = rowDU + (size_t)(t + 1) * DI;
      size_t r3 = rowBC + (size_t)(t + 1) * 48;
      dt_ = DELTA[r2]; u_ = XI[r2]; bt_ = DBC[r3];
    }
    float dA = __expf(dt_c * An);
    h = fmaf(dA, h, dt_c * u_c * bt_c);
    sdt += dt_c;
  }
  HEND[((size_t)chunk * NCHAIN + chain) * 16 + n] = h;
  if (n == 0) SDT[chunk * NCHAIN + chain] = sdt;
}

// ---------------------------------------------------------------------------
// pass 2: scan across chunks per chain: h_init[c] = Aprod[c-1]*h_init[c-1]+h_end[c-1]
// Aprod over a chunk = exp(An * sum_dt). grid: 256 blocks.
// ---------------------------------------------------------------------------
__global__ __launch_bounds__(256) void scan2_kernel(
    const float* __restrict__ HEND, const float* __restrict__ SDT,
    const float* __restrict__ Alog, float* __restrict__ HINIT)
{
  const int tid = threadIdx.x;
  const int cl = tid >> 4, n = tid & 15;
  const int chain = blockIdx.x * 16 + cl;
  const int dir = chain >> 11;
  const int d   = chain & 511;
  const float An = -__expf(Alog[((size_t)(dir * DI + d)) * 16 + n]);
  float h = 0.f;
#pragma unroll
  for (int c = 0; c < NCH; ++c) {
    size_t o = ((size_t)c * NCHAIN + chain) * 16 + n;
    HINIT[o] = h;
    float ap = __expf(An * SDT[c * NCHAIN + chain]);
    h = fmaf(ap, h, HEND[o]);
  }
}

// ---------------------------------------------------------------------------
// pass 3: recompute recurrence per chunk from h_init, emit y via LDS transpose.
// grid: 2048 blocks.
// ---------------------------------------------------------------------------
__global__ __launch_bounds__(256) void scan3_kernel(
    const float* __restrict__ DELTA, const float* __restrict__ XI,
    const float* __restrict__ DBC, const float* __restrict__ Alog,
    const float* __restrict__ HINIT, float* __restrict__ YS)
{
  __shared__ float hc[16 * 272];
  const int tid = threadIdx.x;
  const int cl = tid >> 4, n = tid & 15;
  const int chain = (blockIdx.x & 255) * 16 + cl;
  const int chunk = blockIdx.x >> 8;
  const int dir = chain >> 11;
  const int b   = (chain >> 9) & 3;
  const int d   = chain & 511;

  const float An = -__expf(Alog[((size_t)(dir * DI + d)) * 16 + n]);
  const int t0g = chunk * CHL;
  const size_t rowDU = ((size_t)(dir * BB + b) * LL + t0g) * DI + d;
  const size_t rowBC = ((size_t)(dir * BB + b) * LL + t0g) * 48 + 16 + n;

  float h = HINIT[((size_t)chunk * NCHAIN + chain) * 16 + n];
  float dt_ = DELTA[rowDU], u_ = XI[rowDU];
  float bt_ = DBC[rowBC],  ct_ = DBC[rowBC + 16];

  for (int t0 = 0; t0 < CHL; t0 += 16) {
#pragma unroll
    for (int tt = 0; tt < 16; ++tt) {
      float dt_c = dt_, u_c = u_, bt_c = bt_, ct_c = ct_;
      int tn = t0 + tt + 1;
      if (tn < CHL) {
        size_t r2 = rowDU + (size_t)tn * DI;
        size_t r3 = rowBC + (size_t)tn * 48;
        dt_ = DELTA[r2]; u_ = XI[r2]; bt_ = DBC[r3]; ct_ = DBC[r3 + 16];
      }
      float dA = __expf(dt_c * An);
      h = fmaf(dA, h, dt_c * u_c * bt_c);
      hc[cl * 272 + tt * 17 + n] = h * ct_c;
    }
    __builtin_amdgcn_sched_barrier(0);
    float y = 0.f;
#pragma unroll
    for (int j = 0; j < 16; ++j) y += hc[cl * 272 + n * 17 + j];
    __builtin_amdgcn_sched_barrier(0);
    YS[rowDU + (size_t)(t0 + n) * DI] = y;
  }
}

// ---------------------------------------------------------------------------
// gating: G16 = bf16((YS + XI*D) * silu(z))
// ---------------------------------------------------------------------------
__global__ __launch_bounds__(256) void gate_kernel(
    const float* __restrict__ YS, const float* __restrict__ XI,
    const float* __restrict__ XZ, const float* __restrict__ Dp,
    short* __restrict__ G16)
{
  int idx = blockIdx.x * 256 + threadIdx.x;
  int d = idx & 511;
  int r = idx >> 9;
  int dir = r >> 13;
  float z = XZ[(size_t)r * 1024 + 512 + d];
  float y = YS[idx] + XI[idx] * Dp[dir * DI + d];
  G16[idx] = f2bf(y * fsilu(z));
}

// ---------------------------------------------------------------------------
// dual AddNorm combine: S16 = bf16(LN0(x+f) + LN1(x+bwd)). one block per (b,t).
// ---------------------------------------------------------------------------
__global__ __launch_bounds__(256) void ln_combine_kernel(
    const float* __restrict__ MOUT, const float* __restrict__ x,
    const float* __restrict__ ln_g, const float* __restrict__ ln_b,
    short* __restrict__ S16)
{
  int row = blockIdx.x;
  int m = threadIdx.x;
  size_t i0 = (size_t)row * DM + m;
  float xv = x[i0];
  float s1 = xv + MOUT[i0];
  float s2 = xv + MOUT[(size_t)BL * DM + i0];
  float a1 = s1, q1 = s1 * s1, a2 = s2, q2 = s2 * s2;
  for (int off = 32; off; off >>= 1) {
    a1 += __shfl_xor(a1, off); q1 += __shfl_xor(q1, off);
    a2 += __shfl_xor(a2, off); q2 += __shfl_xor(q2, off);
  }
  __shared__ float red[4][4];
  int w = m >> 6;
  if ((m & 63) == 0) { red[w][0] = a1; red[w][1] = q1; red[w][2] = a2; red[w][3] = q2; }
  __syncthreads();
  a1 = red[0][0] + red[1][0] + red[2][0] + red[3][0];
  q1 = red[0][1] + red[1][1] + red[2][1] + red[3][1];
  a2 = red[0][2] + red[1][2] + red[2][2] + red[3][2];
  q2 = red[0][3] + red[1][3] + red[2][3] + red[3][3];
  const float inv = 1.f / 256.f;
  float mu1 = a1 * inv, mu2 = a2 * inv;
  float v1 = q1 * inv - mu1 * mu1, v2 = q2 * inv - mu2 * mu2;
  float r1 = rsqrtf(v1 + EPSV), r2 = rsqrtf(v2 + EPSV);
  float out = (s1 - mu1) * r1 * ln_g[m] + ln_b[m] +
              (s2 - mu2) * r2 * ln_g[DM + m] + ln_b[DM + m];
  S16[i0] = f2bf(out);
}

}  // namespace

// ---------------------------------------------------------------------------
// workspace (floats):
//   XZ    @ 0          16,777,216  (2,B,L,1024)  [bf16 H16 after gate]
//   XI    @ 16777216    8,388,608  (2,B,L,512)   [fp32 MOUT after gate]
//   DBC   @ 25165824      786,432  (2,B,L,48)
//   DELTA @ 25952256    8,388,608  (2,B,L,512)   [bf16 G16 after scan]
//   YS    @ 34340864    8,388,608  (2,B,L,512)   [bf16 S16 after gate]
//   X16   @ 42729472    1,048,576  (bf16 x)
//   W16   @ 43778048      655,360  (bf16 weights)
//   HEND  @ 44433408      524,288  (8,4096,16)
//   HINIT @ 44957696      524,288  (8,4096,16)
//   SDT   @ 45481984       32,768  (8,4096)
// total 45,514,752 floats = 182.1 MB
// ---------------------------------------------------------------------------
extern "C" void kernel_launch(void* const* d_in, const int* in_sizes, int n_in,
                              void* d_out, int out_size, void* d_ws, size_t ws_size,
                              hipStream_t stream) {
  (void)in_sizes; (void)n_in; (void)out_size; (void)ws_size;
  const float* x      = (const float*)d_in[0];
  const float* in_w   = (const float*)d_in[1];
  const float* conv_w = (const float*)d_in[2];
  const float* conv_b = (const float*)d_in[3];
  const float* xproj_w= (const float*)d_in[4];
  const float* dt_w   = (const float*)d_in[5];
  const float* dt_b   = (const float*)d_in[6];
  const float* Alog   = (const float*)d_in[7];
  const float* Dp     = (const float*)d_in[8];
  const float* out_w  = (const float*)d_in[9];
  const float* bn_g   = (const float*)d_in[10];
  const float* bn_b   = (const float*)d_in[11];
  const float* bn_m   = (const float*)d_in[12];
  const float* bn_v   = (const float*)d_in[13];
  const float* ln_g   = (const float*)d_in[14];
  const float* ln_b   = (const float*)d_in[15];
  const float* w1     = (const float*)d_in[16];
  const float* b1     = (const float*)d_in[17];
  const float* w2     = (const float*)d_in[18];
  const float* b2     = (const float*)d_in[19];

  float* ws    = (float*)d_ws;
  float* XZ    = ws;
  float* XI    = ws + 16777216;
  float* DBC   = ws + 25165824;
  float* DELTA = ws + 25952256;
  float* YS    = ws + 34340864;
  short* X16   = (short*)(ws + 42729472);
  short* W16   = (short*)(ws + 43778048);
  short* IN16  = W16;
  short* OUT16 = W16 + 524288;
  short* W1_16 = W16 + 786432;
  short* W2_16 = W16 + 1048576;
  float* HEND  = ws + 44433408;
  float* HINIT = ws + 44957696;
  float* SDT   = ws + 45481984;
  short* G16   = (short*)DELTA;       // DELTA dead after scan
  float* MOUT  = XI;                  // XI dead after gate
  short* S16   = (short*)YS;          // YS dead after gate
  short* H16   = (short*)XZ;          // XZ dead after gate
  float* OUT   = (float*)d_out;

  dim3 blk(256);

  // 0. bf16 conversions (x + 4 weight tensors)
  cvt_kernel<<<2048, blk, 0, stream>>>(x, X16, 2097152);
  cvt_kernel<<<512,  blk, 0, stream>>>(in_w, IN16, 524288);
  cvt_kernel<<<256,  blk, 0, stream>>>(out_w, OUT16, 262144);
  cvt_kernel<<<256,  blk, 0, stream>>>(w1, W1_16, 262144);
  cvt_kernel<<<256,  blk, 0, stream>>>(w2, W2_16, 262144);

  // 1. in_proj (both dirs, flip via row map) -> XZ fp32
  mgemm<0><<<dim3(8, 128), blk, 0, stream>>>(X16, IN16, XZ, nullptr, 1024, 256,
      nullptr, nullptr, nullptr, nullptr, nullptr, nullptr);
  // 2. depthwise conv + SiLU -> XI
  conv_silu_kernel<<<32768, blk, 0, stream>>>(XZ, conv_w, conv_b, XI);
  // 3. x_proj -> DBC
  xproj_kernel<<<256, blk, 0, stream>>>(XI, xproj_w, DBC);
  // 4. dt proj + softplus -> DELTA
  dtproj_kernel<<<16384, blk, 0, stream>>>(DBC, dt_w, dt_b, DELTA);
  // 5. chunked SSM scan -> YS
  scan1_kernel<<<2048, blk, 0, stream>>>(DELTA, XI, DBC, Alog, HEND, SDT);
  scan2_kernel<<<256,  blk, 0, stream>>>(HEND, SDT, Alog, HINIT);
  scan3_kernel<<<2048, blk, 0, stream>>>(DELTA, XI, DBC, Alog, HINIT, YS);
  // 6. gate -> G16 (bf16, overwrites DELTA)
  gate_kernel<<<32768, blk, 0, stream>>>(YS, XI, XZ, Dp, G16);
  // 7. out_proj + BN(dir) + un-flip -> MOUT (fp32, overwrites XI)
  mgemm<1><<<dim3(2, 128), blk, 0, stream>>>(G16, OUT16, MOUT, nullptr, 256, 512,
      bn_g, bn_b, bn_m, bn_v, nullptr, nullptr);
  // 8. dual AddNorm combine -> S16 (bf16, overwrites YS)
  ln_combine_kernel<<<8192, blk, 0, stream>>>(MOUT, x, ln_g, ln_b, S16);
  // 9. FF1 (+bias, ReLU) -> H16 (bf16, overwrites XZ)
  mgemm<2><<<dim3(8, 64), blk, 0, stream>>>(S16, W1_16, nullptr, H16, 1024, 256,
      b1, nullptr, nullptr, nullptr, nullptr, nullptr);
  // 10. FF2 (+bias, BN[2], +x) -> OUT fp32
  mgemm<3><<<dim3(2, 64), blk, 0, stream>>>(H16, W2_16, OUT, nullptr, 256, 1024,
      b2, bn_g, bn_b, bn_m, bn_v, x);
}

// Round 4
// 352.599 us; speedup vs baseline: 1.1398x; 1.1398x over previous
//
#include <hip/hip_runtime.h>
#include <hip/hip_bf16.h>
#include <cstdint>
#include <cstddef>

namespace {

constexpr int BB  = 4;      // batch
constexpr int LL  = 2048;   // seq
constexpr int DM  = 256;    // d_model
constexpr int DI  = 512;    // d_inner
constexpr int DFF = 1024;
constexpr float EPSV = 1e-5f;
constexpr int BL  = BB * LL;     // 8192 rows per direction
constexpr int M2  = 2 * BL;      // 16384 rows (both dirs)
constexpr int NCH = 8;           // scan chunks
constexpr int CHL = LL / NCH;    // 256 timesteps per chunk
constexpr int NCHAIN = 2 * BB * DI;   // 4096 scan chains

typedef __attribute__((ext_vector_type(8))) short bf16x8;
typedef __attribute__((ext_vector_type(4))) float f32x4;

__device__ __forceinline__ float fsilu(float v) { return v / (1.f + __expf(-v)); }

__device__ __forceinline__ short f2bf(float f) {
  union { float f; uint32_t u; } v; v.f = f;
  uint32_t r = (v.u + 0x7fffu + ((v.u >> 16) & 1u)) >> 16;
  return (short)r;
}

__device__ __forceinline__ void gld16(const short* g, short* l) {
  __builtin_amdgcn_global_load_lds(
      (const __attribute__((address_space(1))) void*)g,
      (__attribute__((address_space(3))) void*)l, 16, 0, 0);
}

__device__ __forceinline__ void gldf16(const float* g, float* l) {
  __builtin_amdgcn_global_load_lds(
      (const __attribute__((address_space(1))) void*)g,
      (__attribute__((address_space(3))) void*)l, 16, 0, 0);
}

// ---------------------------------------------------------------------------
// f32 -> bf16 convert, 4 elems/thread, n % 1024 == 0
// ---------------------------------------------------------------------------
__global__ __launch_bounds__(256) void cvt_kernel(
    const float* __restrict__ in, short* __restrict__ out, int n)
{
  int i = (blockIdx.x * 256 + threadIdx.x) * 4;
  if (i >= n) return;
  float4 v = *reinterpret_cast<const float4*>(in + i);
  ushort4 o;
  o.x = (unsigned short)f2bf(v.x); o.y = (unsigned short)f2bf(v.y);
  o.z = (unsigned short)f2bf(v.z); o.w = (unsigned short)f2bf(v.w);
  *reinterpret_cast<ushort4*>(out + i) = o;
}

// ---------------------------------------------------------------------------
// bf16 MFMA GEMM, 128x128 tile, BK=32, 4 waves of 64x64, fp32 accum.
// ---------------------------------------------------------------------------
template <int EP>
__global__ __launch_bounds__(256) void mgemm(
    const short* __restrict__ A, const short* __restrict__ W,
    float* __restrict__ Cf, short* __restrict__ Ch, int N, int K,
    const float* __restrict__ P0, const float* __restrict__ P1,
    const float* __restrict__ P2, const float* __restrict__ P3,
    const float* __restrict__ P4, const float* __restrict__ P5)
{
  __shared__ short As[128 * 32];
  __shared__ short Bs[128 * 32];
  const int tid  = threadIdx.x;
  const int lane = tid & 63, wv = tid >> 6;
  const int wrow = (wv >> 1) * 64, wcol = (wv & 1) * 64;
  const int row0 = blockIdx.y * 128, col0 = blockIdx.x * 128;
  const int dir  = (EP == 0 || EP == 1) ? (row0 >= BL ? 1 : 0) : 0;
  const short* Wp = W + (size_t)dir * (size_t)N * (size_t)K;

  f32x4 acc[4][4];
#pragma unroll
  for (int m = 0; m < 4; ++m)
#pragma unroll
    for (int n = 0; n < 4; ++n) acc[m][n] = (f32x4){0.f, 0.f, 0.f, 0.f};

  for (int k0 = 0; k0 < K; k0 += 32) {
#pragma unroll
    for (int s = 0; s < 2; ++s) {
      int f = s * 256 + wv * 64 + lane;      // [0,512)
      int rr = f >> 2, kc = f & 3;           // tile row, 16B chunk along k
      const short* asrc;
      if (EP == 0) {
        int r  = row0 + rr;
        int rb = r & (BL - 1);
        int b = rb >> 11, t = rb & (LL - 1);
        int torig = dir ? (LL - 1 - t) : t;
        asrc = A + ((size_t)(b * LL + torig)) * K + k0 + kc * 8;
      } else {
        asrc = A + (size_t)(row0 + rr) * K + k0 + kc * 8;
      }
      const short* bsrc = Wp + (size_t)(col0 + rr) * K + k0 + kc * 8;
      gld16(asrc, &As[(s * 256 + wv * 64) * 8]);   // wave-uniform LDS base
      gld16(bsrc, &Bs[(s * 256 + wv * 64) * 8]);
    }
    __syncthreads();
    bf16x8 af[4], bfr[4];
    const int krow = (lane >> 4) * 8;
#pragma unroll
    for (int m = 0; m < 4; ++m)
      af[m] = *reinterpret_cast<const bf16x8*>(&As[(wrow + m * 16 + (lane & 15)) * 32 + krow]);
#pragma unroll
    for (int n = 0; n < 4; ++n)
      bfr[n] = *reinterpret_cast<const bf16x8*>(&Bs[(wcol + n * 16 + (lane & 15)) * 32 + krow]);
#pragma unroll
    for (int m = 0; m < 4; ++m)
#pragma unroll
      for (int n = 0; n < 4; ++n)
        acc[m][n] = __builtin_amdgcn_mfma_f32_16x16x32_bf16(af[m], bfr[n], acc[m][n], 0, 0, 0);
    __syncthreads();
  }

  // epilogue: C/D layout col=lane&15, row=(lane>>4)*4+reg
#pragma unroll
  for (int m = 0; m < 4; ++m) {
#pragma unroll
    for (int i = 0; i < 4; ++i) {
      int r = row0 + wrow + m * 16 + (lane >> 4) * 4 + i;
      size_t obase;
      if (EP == 1) {
        int rb = r & (BL - 1);
        int b = rb >> 11, t = rb & (LL - 1);
        int torig = dir ? (LL - 1 - t) : t;
        obase = ((size_t)(dir * BB + b) * LL + torig) * DM;
      } else {
        obase = (size_t)r * N;
      }
#pragma unroll
      for (int n = 0; n < 4; ++n) {
        int c = col0 + wcol + n * 16 + (lane & 15);
        float val = acc[m][n][i];
        if (EP == 1) {
          int o = dir * DM + c;
          val = (val - P2[o]) * rsqrtf(P3[o] + EPSV) * P0[o] + P1[o];
          Cf[obase + c] = val;
        } else if (EP == 2) {
          val = fmaxf(val + P0[c], 0.f);
          Ch[obase + c] = f2bf(val);
        } else if (EP == 3) {
          val = val + P0[c];
          int o = 2 * DM + c;
          val = (val - P3[o]) * rsqrtf(P4[o] + EPSV) * P1[o] + P2[o];
          val += P5[obase + c];
          Cf[obase + c] = val;
        } else {
          Cf[obase + c] = val;
        }
      }
    }
  }
}

// ---------------------------------------------------------------------------
// causal depthwise conv (taps=4) + bias + SiLU, float4 over channels.
// ---------------------------------------------------------------------------
__global__ __launch_bounds__(256) void conv_silu_kernel(
    const float* __restrict__ XZ, const float* __restrict__ cw,
    const float* __restrict__ cb, float* __restrict__ XI)
{
  int idx = blockIdx.x * 256 + threadIdx.x;   // [0, 16.7M/4)
  int dq = (idx & 127) * 4;                   // channel group base
  int r  = idx >> 7;                          // (dir*4+b)*2048 + t
  int t  = r & (LL - 1);
  int db = r >> 11;
  int dir = db >> 2;
  size_t base = (size_t)db * LL * 1024 + dq;  // x-half of XZ, t'=0
  float4 wc0 = *reinterpret_cast<const float4*>(cw + (size_t)(dir * DI + dq + 0) * 4);
  float4 wc1 = *reinterpret_cast<const float4*>(cw + (size_t)(dir * DI + dq + 1) * 4);
  float4 wc2 = *reinterpret_cast<const float4*>(cw + (size_t)(dir * DI + dq + 2) * 4);
  float4 wc3 = *reinterpret_cast<const float4*>(cw + (size_t)(dir * DI + dq + 3) * 4);
  float4 bv  = *reinterpret_cast<const float4*>(cb + dir * DI + dq);
  float a0 = bv.x, a1 = bv.y, a2 = bv.z, a3 = bv.w;
#pragma unroll
  for (int j = 0; j < 4; ++j) {
    int tp = t - 3 + j;
    if (tp >= 0) {
      float4 xv = *reinterpret_cast<const float4*>(XZ + base + (size_t)tp * 1024);
      float w0j = j == 0 ? wc0.x : j == 1 ? wc0.y : j == 2 ? wc0.z : wc0.w;
      float w1j = j == 0 ? wc1.x : j == 1 ? wc1.y : j == 2 ? wc1.z : wc1.w;
      float w2j = j == 0 ? wc2.x : j == 1 ? wc2.y : j == 2 ? wc2.z : wc2.w;
      float w3j = j == 0 ? wc3.x : j == 1 ? wc3.y : j == 2 ? wc3.z : wc3.w;
      a0 = fmaf(w0j, xv.x, a0); a1 = fmaf(w1j, xv.y, a1);
      a2 = fmaf(w2j, xv.z, a2); a3 = fmaf(w3j, xv.w, a3);
    }
  }
  float4 o = make_float4(fsilu(a0), fsilu(a1), fsilu(a2), fsilu(a3));
  *reinterpret_cast<float4*>(XI + (size_t)r * DI + dq) = o;
}

// ---------------------------------------------------------------------------
// xproj: DBC(M2 x 48) = XI(M2 x 512) @ xproj_w(dir)^T.  64-row tiles, fp32.
// ---------------------------------------------------------------------------
__global__ __launch_bounds__(256) void xproj_kernel(
    const float* __restrict__ XI, const float* __restrict__ W, float* __restrict__ DBC)
{
  __shared__ __align__(16) float As[64 * 68];   // [k][row]
  __shared__ __align__(16) float Ws[64 * 52];   // [k][col]
  const int tid = threadIdx.x;
  const int row0 = blockIdx.x * 64;
  const int dir = row0 >= BL ? 1 : 0;
  const float* Wp = W + (size_t)dir * 48 * DI;
  const int TX = tid & 15, TY = tid >> 4;
  float acc[4][3];
#pragma unroll
  for (int i = 0; i < 4; ++i)
#pragma unroll
    for (int j = 0; j < 3; ++j) acc[i][j] = 0.f;

  for (int k0 = 0; k0 < DI; k0 += 64) {
#pragma unroll
    for (int s = 0; s < 4; ++s) {
      int f = tid + s * 256;
      int kq = f & 15, m = f >> 4;
      float4 v = *reinterpret_cast<const float4*>(XI + (size_t)(row0 + m) * DI + k0 + kq * 4);
      int kk = kq * 4;
      As[(kk + 0) * 68 + m] = v.x; As[(kk + 1) * 68 + m] = v.y;
      As[(kk + 2) * 68 + m] = v.z; As[(kk + 3) * 68 + m] = v.w;
    }
#pragma unroll
    for (int s = 0; s < 3; ++s) {
      int f = tid + s * 256;
      int kq = f & 15, n = f >> 4;
      float4 v = *reinterpret_cast<const float4*>(Wp + (size_t)n * DI + k0 + kq * 4);
      int kk = kq * 4;
      Ws[(kk + 0) * 52 + n] = v.x; Ws[(kk + 1) * 52 + n] = v.y;
      Ws[(kk + 2) * 52 + n] = v.z; Ws[(kk + 3) * 52 + n] = v.w;
    }
    __syncthreads();
    for (int k = 0; k < 64; ++k) {
      float a[4], b[3];
#pragma unroll
      for (int i = 0; i < 4; ++i) a[i] = As[k * 68 + TY * 4 + i];
#pragma unroll
      for (int j = 0; j < 3; ++j) b[j] = Ws[k * 52 + TX * 3 + j];
#pragma unroll
      for (int i = 0; i < 4; ++i)
#pragma unroll
        for (int j = 0; j < 3; ++j) acc[i][j] = fmaf(a[i], b[j], acc[i][j]);
    }
    __syncthreads();
  }
#pragma unroll
  for (int i = 0; i < 4; ++i)
#pragma unroll
    for (int j = 0; j < 3; ++j)
      DBC[(size_t)(row0 + TY * 4 + i) * 48 + TX * 3 + j] = acc[i][j];
}

// ---------------------------------------------------------------------------
// delta = softplus(dt @ dt_w^T + dt_b); one block per (dir,b,t) row
// ---------------------------------------------------------------------------
__global__ __launch_bounds__(256) void dtproj_kernel(
    const float* __restrict__ DBC, const float* __restrict__ dt_w,
    const float* __restrict__ dt_b, float* __restrict__ DELTA)
{
  int row = blockIdx.x;            // [0, 16384)
  int dir = row >> 13;
  __shared__ float dtv[16];
  if (threadIdx.x < 16) dtv[threadIdx.x] = DBC[(size_t)row * 48 + threadIdx.x];
  __syncthreads();
  for (int dd = threadIdx.x; dd < DI; dd += 256) {
    const float* wrow = dt_w + (size_t)(dir * DI + dd) * 16;
    float a = dt_b[dir * DI + dd];
#pragma unroll
    for (int r = 0; r < 16; ++r) a = fmaf(dtv[r], wrow[r], a);
    float sp = (a > 20.f) ? a : log1pf(__expf(a));
    DELTA[(size_t)row * DI + dd] = sp;
  }
}

// ---------------------------------------------------------------------------
// Chunked scan pass 1: per (chain,chunk) recurrence from h0=0 -> HEND, SDT.
// LDS-staged 16-step windows, double buffered, one gld16 per wave per array.
// grid 2048: block = 16 chains (16 consecutive d of one (dir,b)), chunk = bid>>8
// ---------------------------------------------------------------------------
__global__ __launch_bounds__(256) void scan1_kernel(
    const float* __restrict__ DELTA, const float* __restrict__ XI,
    const float* __restrict__ DBC, const float* __restrict__ Alog,
    float* __restrict__ HEND, float* __restrict__ SDT)
{
  __shared__ float Dl[2][256];
  __shared__ float Xl[2][256];
  __shared__ float Bl[2][256];
  const int tid = threadIdx.x;
  const int lane = tid & 63, wv = tid >> 6;
  const int cl = tid >> 4, n = tid & 15;
  const int blk = blockIdx.x & 255, chunk = blockIdx.x >> 8;
  const int chain0 = blk * 16;
  const int dir = chain0 >> 11, b = (chain0 >> 9) & 3;
  const int d0 = chain0 & 511;
  const int d  = d0 + cl;

  const float An = -__expf(Alog[((size_t)(dir * DI + d)) * 16 + n]);
  const size_t seq = (size_t)(dir * BB + b) * LL + chunk * CHL;
  const size_t baseDU = seq * DI;
  const size_t baseBC = seq * 48;

  const int stt = lane >> 2, sq = lane & 3;
  float h = 0.f, sdt = 0.f;

  // stage window 0
  {
    int t = stt;
    if (wv == 0)      gldf16(DELTA + baseDU + (size_t)t * DI + d0 + sq * 4, &Dl[0][0]);
    else if (wv == 1) gldf16(XI    + baseDU + (size_t)t * DI + d0 + sq * 4, &Xl[0][0]);
    else if (wv == 2) gldf16(DBC   + baseBC + (size_t)t * 48 + 16 + sq * 4, &Bl[0][0]);
  }
  __syncthreads();

  for (int w = 0; w < CHL / 16; ++w) {
    int bb = w & 1;
    if (w + 1 < CHL / 16) {
      int t = (w + 1) * 16 + stt;
      if (wv == 0)      gldf16(DELTA + baseDU + (size_t)t * DI + d0 + sq * 4, &Dl[bb ^ 1][0]);
      else if (wv == 1) gldf16(XI    + baseDU + (size_t)t * DI + d0 + sq * 4, &Xl[bb ^ 1][0]);
      else if (wv == 2) gldf16(DBC   + baseBC + (size_t)t * 48 + 16 + sq * 4, &Bl[bb ^ 1][0]);
    }
#pragma unroll
    for (int tt = 0; tt < 16; ++tt) {
      float dt = Dl[bb][tt * 16 + cl];
      float u  = Xl[bb][tt * 16 + cl];
      float bt = Bl[bb][tt * 16 + n];
      float dA = __expf(dt * An);
      h = fmaf(dA, h, dt * u * bt);
      sdt += dt;
    }
    __syncthreads();
  }
  HEND[((size_t)chunk * NCHAIN + chain0 + cl) * 16 + n] = h;
  if (n == 0) SDT[chunk * NCHAIN + chain0 + cl] = sdt;
}

// ---------------------------------------------------------------------------
// pass 2: scan across chunks per chain. grid: 256 blocks.
// ---------------------------------------------------------------------------
__global__ __launch_bounds__(256) void scan2_kernel(
    const float* __restrict__ HEND, const float* __restrict__ SDT,
    const float* __restrict__ Alog, float* __restrict__ HINIT)
{
  const int tid = threadIdx.x;
  const int cl = tid >> 4, n = tid & 15;
  const int chain = blockIdx.x * 16 + cl;
  const int dir = chain >> 11;
  const int d   = chain & 511;
  const float An = -__expf(Alog[((size_t)(dir * DI + d)) * 16 + n]);
  float h = 0.f;
#pragma unroll
  for (int c = 0; c < NCH; ++c) {
    size_t o = ((size_t)c * NCHAIN + chain) * 16 + n;
    HINIT[o] = h;
    float ap = __expf(An * SDT[c * NCHAIN + chain]);
    h = fmaf(ap, h, HEND[o]);
  }
}

// ---------------------------------------------------------------------------
// pass 3: recurrence from HINIT + fused gate -> G16 bf16.
// Staged windows: DELTA, XI, B, C, Z(=XZ z-half). grid 2048.
// ---------------------------------------------------------------------------
__global__ __launch_bounds__(256) void scan3_kernel(
    const float* __restrict__ DELTA, const float* __restrict__ XI,
    const float* __restrict__ DBC, const float* __restrict__ Alog,
    const float* __restrict__ HINIT, const float* __restrict__ XZ,
    const float* __restrict__ Dp, short* __restrict__ G16)
{
  __shared__ float hc[16 * 272];
  __shared__ float Dl[2][256];
  __shared__ float Xl[2][256];
  __shared__ float Bl[2][256];
  __shared__ float Cl[2][256];
  __shared__ float Zl[2][256];
  const int tid = threadIdx.x;
  const int lane = tid & 63, wv = tid >> 6;
  const int cl = tid >> 4, n = tid & 15;
  const int blk = blockIdx.x & 255, chunk = blockIdx.x >> 8;
  const int chain0 = blk * 16;
  const int dir = chain0 >> 11, b = (chain0 >> 9) & 3;
  const int d0 = chain0 & 511;
  const int d  = d0 + cl;

  const float An = -__expf(Alog[((size_t)(dir * DI + d)) * 16 + n]);
  const size_t seq = (size_t)(dir * BB + b) * LL + chunk * CHL;
  const size_t baseDU = seq * DI;
  const size_t baseBC = seq * 48;
  const size_t baseZ  = seq * 1024 + 512;
  const float Dskip = Dp[dir * DI + d];

  float h = HINIT[((size_t)chunk * NCHAIN + chain0 + cl) * 16 + n];

  const int stt = lane >> 2, sq = lane & 3;

  // stage window 0
  {
    int t = stt;
    if (wv == 0) {
      gldf16(DELTA + baseDU + (size_t)t * DI + d0 + sq * 4, &Dl[0][0]);
      gldf16(XZ + baseZ + (size_t)t * 1024 + d0 + sq * 4, &Zl[0][0]);
    } else if (wv == 1) {
      gldf16(XI + baseDU + (size_t)t * DI + d0 + sq * 4, &Xl[0][0]);
    } else if (wv == 2) {
      gldf16(DBC + baseBC + (size_t)t * 48 + 16 + sq * 4, &Bl[0][0]);
    } else {
      gldf16(DBC + baseBC + (size_t)t * 48 + 32 + sq * 4, &Cl[0][0]);
    }
  }
  __syncthreads();

  for (int w = 0; w < CHL / 16; ++w) {
    int bb = w & 1;
    if (w + 1 < CHL / 16) {
      int t = (w + 1) * 16 + stt;
      if (wv == 0) {
        gldf16(DELTA + baseDU + (size_t)t * DI + d0 + sq * 4, &Dl[bb ^ 1][0]);
        gldf16(XZ + baseZ + (size_t)t * 1024 + d0 + sq * 4, &Zl[bb ^ 1][0]);
      } else if (wv == 1) {
        gldf16(XI + baseDU + (size_t)t * DI + d0 + sq * 4, &Xl[bb ^ 1][0]);
      } else if (wv == 2) {
        gldf16(DBC + baseBC + (size_t)t * 48 + 16 + sq * 4, &Bl[bb ^ 1][0]);
      } else {
        gldf16(DBC + baseBC + (size_t)t * 48 + 32 + sq * 4, &Cl[bb ^ 1][0]);
      }
    }
#pragma unroll
    for (int tt = 0; tt < 16; ++tt) {
      float dt = Dl[bb][tt * 16 + cl];
      float u  = Xl[bb][tt * 16 + cl];
      float bt = Bl[bb][tt * 16 + n];
      float ct = Cl[bb][tt * 16 + n];
      float dA = __expf(dt * An);
      h = fmaf(dA, h, dt * u * bt);
      hc[cl * 272 + tt * 17 + n] = h * ct;
    }
    __builtin_amdgcn_sched_barrier(0);
    float y = 0.f;
#pragma unroll
    for (int j = 0; j < 16; ++j) y += hc[cl * 272 + n * 17 + j];
    __builtin_amdgcn_sched_barrier(0);
    // fused gate for timestep t = w*16 + n, channel d
    float u_n = Xl[bb][n * 16 + cl];
    float z   = Zl[bb][n * 16 + cl];
    float yy  = (y + u_n * Dskip) * fsilu(z);
    G16[baseDU + (size_t)(w * 16 + n) * DI + d] = f2bf(yy);
    __syncthreads();
  }
}

// ---------------------------------------------------------------------------
// dual AddNorm combine: S16 = bf16(LN0(x+f) + LN1(x+bwd)). one block per (b,t).
// ---------------------------------------------------------------------------
__global__ __launch_bounds__(256) void ln_combine_kernel(
    const float* __restrict__ MOUT, const float* __restrict__ x,
    const float* __restrict__ ln_g, const float* __restrict__ ln_b,
    short* __restrict__ S16)
{
  int row = blockIdx.x;
  int m = threadIdx.x;
  size_t i0 = (size_t)row * DM + m;
  float xv = x[i0];
  float s1 = xv + MOUT[i0];
  float s2 = xv + MOUT[(size_t)BL * DM + i0];
  float a1 = s1, q1 = s1 * s1, a2 = s2, q2 = s2 * s2;
  for (int off = 32; off; off >>= 1) {
    a1 += __shfl_xor(a1, off); q1 += __shfl_xor(q1, off);
    a2 += __shfl_xor(a2, off); q2 += __shfl_xor(q2, off);
  }
  __shared__ float red[4][4];
  int w = m >> 6;
  if ((m & 63) == 0) { red[w][0] = a1; red[w][1] = q1; red[w][2] = a2; red[w][3] = q2; }
  __syncthreads();
  a1 = red[0][0] + red[1][0] + red[2][0] + red[3][0];
  q1 = red[0][1] + red[1][1] + red[2][1] + red[3][1];
  a2 = red[0][2] + red[1][2] + red[2][2] + red[3][2];
  q2 = red[0][3] + red[1][3] + red[2][3] + red[3][3];
  const float inv = 1.f / 256.f;
  float mu1 = a1 * inv, mu2 = a2 * inv;
  float v1 = q1 * inv - mu1 * mu1, v2 = q2 * inv - mu2 * mu2;
  float r1 = rsqrtf(v1 + EPSV), r2 = rsqrtf(v2 + EPSV);
  float out = (s1 - mu1) * r1 * ln_g[m] + ln_b[m] +
              (s2 - mu2) * r2 * ln_g[DM + m] + ln_b[DM + m];
  S16[i0] = f2bf(out);
}

}  // namespace

// ---------------------------------------------------------------------------
// workspace (floats):
//   XZ    @ 0          16,777,216  (2,B,L,1024)  [bf16 H16 after scan3]
//   XI    @ 16777216    8,388,608  (2,B,L,512)   [fp32 MOUT after out_proj]
//   DBC   @ 25165824      786,432  (2,B,L,48)
//   DELTA @ 25952256    8,388,608  (2,B,L,512)
//   YS    @ 34340864    8,388,608  [bf16 G16 from scan3; later bf16 S16]
//   X16   @ 42729472    1,048,576  (bf16 x)
//   W16   @ 43778048      655,360  (bf16 weights)
//   HEND  @ 44433408      524,288  (8,4096,16)
//   HINIT @ 44957696      524,288  (8,4096,16)
//   SDT   @ 45481984       32,768  (8,4096)
// total 45,514,752 floats = 182.1 MB
// ---------------------------------------------------------------------------
extern "C" void kernel_launch(void* const* d_in, const int* in_sizes, int n_in,
                              void* d_out, int out_size, void* d_ws, size_t ws_size,
                              hipStream_t stream) {
  (void)in_sizes; (void)n_in; (void)out_size; (void)ws_size;
  const float* x      = (const float*)d_in[0];
  const float* in_w   = (const float*)d_in[1];
  const float* conv_w = (const float*)d_in[2];
  const float* conv_b = (const float*)d_in[3];
  const float* xproj_w= (const float*)d_in[4];
  const float* dt_w   = (const float*)d_in[5];
  const float* dt_b   = (const float*)d_in[6];
  const float* Alog   = (const float*)d_in[7];
  const float* Dp     = (const float*)d_in[8];
  const float* out_w  = (const float*)d_in[9];
  const float* bn_g   = (const float*)d_in[10];
  const float* bn_b   = (const float*)d_in[11];
  const float* bn_m   = (const float*)d_in[12];
  const float* bn_v   = (const float*)d_in[13];
  const float* ln_g   = (const float*)d_in[14];
  const float* ln_b   = (const float*)d_in[15];
  const float* w1     = (const float*)d_in[16];
  const float* b1     = (const float*)d_in[17];
  const float* w2     = (const float*)d_in[18];
  const float* b2     = (const float*)d_in[19];

  float* ws    = (float*)d_ws;
  float* XZ    = ws;
  float* XI    = ws + 16777216;
  float* DBC   = ws + 25165824;
  float* DELTA = ws + 25952256;
  float* YS    = ws + 34340864;
  short* X16   = (short*)(ws + 42729472);
  short* W16   = (short*)(ws + 43778048);
  short* IN16  = W16;
  short* OUT16 = W16 + 524288;
  short* W1_16 = W16 + 786432;
  short* W2_16 = W16 + 1048576;
  float* HEND  = ws + 44433408;
  float* HINIT = ws + 44957696;
  float* SDT   = ws + 45481984;
  short* G16   = (short*)YS;          // scan3 output (YS region, 16.7M shorts)
  float* MOUT  = XI;                  // XI dead after scan3
  short* S16   = (short*)YS;          // G16 dead after out_proj
  short* H16   = (short*)XZ;          // XZ dead after scan3
  float* OUT   = (float*)d_out;

  dim3 blk(256);

  // 0. bf16 conversions (x + 4 weight tensors)
  cvt_kernel<<<2048, blk, 0, stream>>>(x, X16, 2097152);
  cvt_kernel<<<512,  blk, 0, stream>>>(in_w, IN16, 524288);
  cvt_kernel<<<256,  blk, 0, stream>>>(out_w, OUT16, 262144);
  cvt_kernel<<<256,  blk, 0, stream>>>(w1, W1_16, 262144);
  cvt_kernel<<<256,  blk, 0, stream>>>(w2, W2_16, 262144);

  // 1. in_proj (both dirs, flip via row map) -> XZ fp32
  mgemm<0><<<dim3(8, 128), blk, 0, stream>>>(X16, IN16, XZ, nullptr, 1024, 256,
      nullptr, nullptr, nullptr, nullptr, nullptr, nullptr);
  // 2. depthwise conv + SiLU -> XI (float4)
  conv_silu_kernel<<<16384, blk, 0, stream>>>(XZ, conv_w, conv_b, XI);
  // 3. x_proj -> DBC
  xproj_kernel<<<256, blk, 0, stream>>>(XI, xproj_w, DBC);
  // 4. dt proj + softplus -> DELTA
  dtproj_kernel<<<16384, blk, 0, stream>>>(DBC, dt_w, dt_b, DELTA);
  // 5. chunked SSM scan, gate fused into pass 3 -> G16
  scan1_kernel<<<2048, blk, 0, stream>>>(DELTA, XI, DBC, Alog, HEND, SDT);
  scan2_kernel<<<256,  blk, 0, stream>>>(HEND, SDT, Alog, HINIT);
  scan3_kernel<<<2048, blk, 0, stream>>>(DELTA, XI, DBC, Alog, HINIT, XZ, Dp, G16);
  // 7. out_proj + BN(dir) + un-flip -> MOUT (fp32, overwrites XI)
  mgemm<1><<<dim3(2, 128), blk, 0, stream>>>(G16, OUT16, MOUT, nullptr, 256, 512,
      bn_g, bn_b, bn_m, bn_v, nullptr, nullptr);
  // 8. dual AddNorm combine -> S16 (bf16, overwrites G16 region)
  ln_combine_kernel<<<8192, blk, 0, stream>>>(MOUT, x, ln_g, ln_b, S16);
  // 9. FF1 (+bias, ReLU) -> H16 (bf16, overwrites XZ)
  mgemm<2><<<dim3(8, 64), blk, 0, stream>>>(S16, W1_16, nullptr, H16, 1024, 256,
      b1, nullptr, nullptr, nullptr, nullptr, nullptr);
  // 10. FF2 (+bias, BN[2], +x) -> OUT fp32
  mgemm<3><<<dim3(2, 64), blk, 0, stream>>>(H16, W2_16, OUT, nullptr, 256, 1024,
      b2, bn_g, bn_b, bn_m, bn_v, x);
}